// Round 2
// baseline (296.572 us; speedup 1.0000x reference)
//
#include <hip/hip_runtime.h>
#include <hip/hip_bf16.h>
#include <math.h>

// TemporalLayer: 2-entity attention (T=8, N=4096->M=2048/entity, U=128)
// Round 2: barrier-free attn. K/V fragments read directly from global
// (L1/L2-resident, line-perfect), swapped QK^T so softmax is lane-local,
// P via per-wave swizzled LDS (b64 writes). 8 waves/block, 1 block/CU,
// XCD-grouped block decode.
// ws layout (bytes):
//   [0)       qwT/kwT/vwT/fcwT  f16 [4][2][128][128]   (256 KB)
//   [262144)  q16  f16 [2][2048][128]                  (1 MB)
//   [1310720) q32  f32 [2][2048][128]                  (2 MB)
//   [3407872) K16  f16 [2][8][2048][128]               (8 MB)
//   [11796480)Vt16 f16 [2][8][128][2048]               (8 MB)  total 19.25 MB

typedef _Float16 f16;
typedef _Float16 half8 __attribute__((ext_vector_type(8)));
typedef _Float16 half4 __attribute__((ext_vector_type(4)));
typedef float f32x4 __attribute__((ext_vector_type(4)));
typedef float float4v __attribute__((ext_vector_type(4)));

#define OFF_Q16  262144
#define OFF_Q32  1310720
#define OFF_K16  3407872
#define OFF_VT16 11796480

__global__ void prep_weights_kernel(const float* __restrict__ qw, const float* __restrict__ kw,
                                    const float* __restrict__ vw, const float* __restrict__ fcw,
                                    f16* __restrict__ wT) {
  int b = blockIdx.x;                 // 32 blocks: wsel*8 + e*4 + part
  int wsel = b >> 3, e = (b >> 2) & 1, part = b & 3;
  const float* src = (wsel == 0) ? qw : (wsel == 1) ? kw : (wsel == 2) ? vw : fcw;
  src += e * 16384;
  f16* dst = wT + (size_t)wsel * 32768 + e * 16384;
  for (int i = part * 4096 + threadIdx.x; i < (part + 1) * 4096; i += 256) {
    int v = i >> 7, u = i & 127;
    dst[i] = (f16)src[u * 128 + v];   // wT[v][u] = w[u][v]
  }
}

// grid (32, 8, 2): 64 nodes per block, 4 waves x 16 rows
__global__ __launch_bounds__(256) void proj_kernel(
    const float* __restrict__ ns, const int* __restrict__ acc_idx, const int* __restrict__ stock_idx,
    const f16* __restrict__ wT, f16* __restrict__ K16, f16* __restrict__ Vt16,
    f16* __restrict__ q16, float* __restrict__ q32) {
  const int e = blockIdx.z, t = blockIdx.y, nt = blockIdx.x;
  const int tid = threadIdx.x, w = tid >> 6, l = tid & 63;
  const int g = l >> 4, li = l & 15;
  const int* idx = e ? stock_idx : acc_idx;
  const int mA = nt * 64 + w * 16 + li;
  const int gnode = idx[mA];
  const float* srow = ns + ((size_t)t * 4096 + gnode) * 128;
  half8 a[4];
#pragma unroll
  for (int c = 0; c < 4; ++c) {
    const float4v* p = (const float4v*)(srow + c * 32 + g * 8);
    float4v x0 = p[0], x1 = p[1];
    half8 h;
    h[0]=(f16)x0[0]; h[1]=(f16)x0[1]; h[2]=(f16)x0[2]; h[3]=(f16)x0[3];
    h[4]=(f16)x1[0]; h[5]=(f16)x1[1]; h[6]=(f16)x1[2]; h[7]=(f16)x1[3];
    a[c] = h;
  }
  const f16* qwT = wT + 0     + e * 16384;
  const f16* kwT = wT + 32768 + e * 16384;
  const f16* vwT = wT + 65536 + e * 16384;

  // K = s @ kw -> K16[e][t][m][v]
#pragma unroll
  for (int ct = 0; ct < 8; ++ct) {
    f32x4 acc = {0.f, 0.f, 0.f, 0.f};
#pragma unroll
    for (int c = 0; c < 4; ++c) {
      half8 b = *(const half8*)(kwT + (ct * 16 + li) * 128 + c * 32 + g * 8);
      acc = __builtin_amdgcn_mfma_f32_16x16x32_f16(a[c], b, acc, 0, 0, 0);
    }
#pragma unroll
    for (int r = 0; r < 4; ++r) {
      int mrow = nt * 64 + w * 16 + g * 4 + r;
      K16[(((size_t)e * 8 + t) * 2048 + mrow) * 128 + ct * 16 + li] = (f16)acc[r];
    }
  }
  // V = s @ vw -> stored transposed Vt16[e][t][v][m], packed half4 writes
#pragma unroll
  for (int ct = 0; ct < 8; ++ct) {
    f32x4 acc = {0.f, 0.f, 0.f, 0.f};
#pragma unroll
    for (int c = 0; c < 4; ++c) {
      half8 b = *(const half8*)(vwT + (ct * 16 + li) * 128 + c * 32 + g * 8);
      acc = __builtin_amdgcn_mfma_f32_16x16x32_f16(a[c], b, acc, 0, 0, 0);
    }
    half4 pk;
#pragma unroll
    for (int r = 0; r < 4; ++r) pk[r] = (f16)acc[r];
    int m0 = nt * 64 + w * 16 + g * 4;
    *(half4*)(Vt16 + (((size_t)e * 8 + t) * 128 + ct * 16 + li) * 2048 + m0) = pk;
  }
  // q = s[-1] @ qw (f16 + f32)
  if (t == 7) {
#pragma unroll
    for (int ct = 0; ct < 8; ++ct) {
      f32x4 acc = {0.f, 0.f, 0.f, 0.f};
#pragma unroll
      for (int c = 0; c < 4; ++c) {
        half8 b = *(const half8*)(qwT + (ct * 16 + li) * 128 + c * 32 + g * 8);
        acc = __builtin_amdgcn_mfma_f32_16x16x32_f16(a[c], b, acc, 0, 0, 0);
      }
#pragma unroll
      for (int r = 0; r < 4; ++r) {
        int mrow = nt * 64 + w * 16 + g * 4 + r;
        size_t o = ((size_t)e * 2048 + mrow) * 128 + ct * 16 + li;
        q16[o] = (f16)acc[r];
        q32[o] = acc[r];
      }
    }
  }
}

// 256 blocks x 512 threads (8 waves x 16 rows = 128 rows/block). Barrier-free.
__global__ __launch_bounds__(512, 2) void attn_kernel(
    const f16* __restrict__ K16, const f16* __restrict__ Vt16,
    const f16* __restrict__ q16, const float* __restrict__ q32,
    const f16* __restrict__ fcwT, const float* __restrict__ ln_w, const float* __restrict__ ln_b,
    const int* __restrict__ acc_idx, const int* __restrict__ stock_idx,
    float* __restrict__ out) {
  __shared__ __align__(16) char smem[32768];   // 8 waves x 4KB (P: 2KB, As: 4KB)
  const int bid = blockIdx.x;
  const int x = bid & 7, j = bid >> 3;         // x = XCD slot
  const int et = x + 8 * (j >> 4);             // 16 (e,t) groups, 2 per XCD
  const int nt = j & 15;
  const int e = et >> 3, t = et & 7;
  const int n0 = nt * 128;
  const int tid = threadIdx.x, w = tid >> 6, l = tid & 63;
  const int g = l >> 4, li = l & 15;
  const int* idx = e ? stock_idx : acc_idx;

  char* Pw = smem + w * 4096;                  // per-wave scratch

  half8 qa[4];
  {
    const f16* qrow = q16 + ((size_t)e * 2048 + n0 + w * 16 + li) * 128;
#pragma unroll
    for (int c = 0; c < 4; ++c) qa[c] = *(const half8*)(qrow + c * 32 + g * 8);
  }
  float lw[8], lb[8];
#pragma unroll
  for (int ct = 0; ct < 8; ++ct) { lw[ct] = ln_w[ct * 16 + li]; lb[ct] = ln_b[ct * 16 + li]; }

  f32x4 agg[8];
#pragma unroll
  for (int ct = 0; ct < 8; ++ct) agg[ct] = (f32x4){0.f, 0.f, 0.f, 0.f};
  float m_run = -INFINITY, l_run = 0.f;        // stats for q-row n = w*16 + li

  const char* Kg = (const char*)(K16 + ((size_t)e * 8 + t) * 2048 * 128);
  const char* Vg = (const char*)(Vt16 + ((size_t)e * 8 + t) * 128 * 2048);

  for (int mc = 0; mc < 32; ++mc) {
    // S^T = K @ Q^T : sv[ct][r] = S[m = mc*64+ct*16+g*4+r][n = li]
    const char* Kc = Kg + (size_t)mc * 16384;
    float sv[4][4];
#pragma unroll
    for (int ct = 0; ct < 4; ++ct) {
      f32x4 sa = {0.f, 0.f, 0.f, 0.f};
#pragma unroll
      for (int c = 0; c < 4; ++c) {
        half8 bk = *(const half8*)(Kc + (ct * 16 + li) * 256 + g * 16 + c * 64);
        sa = __builtin_amdgcn_mfma_f32_16x16x32_f16(bk, qa[c], sa, 0, 0, 0);
      }
#pragma unroll
      for (int r = 0; r < 4; ++r) sv[ct][r] = sa[r];
    }
    // online softmax: all 16 values for row n=li are in-lane; cross-g shfl x2
    float mx = sv[0][0];
#pragma unroll
    for (int ct = 0; ct < 4; ++ct)
#pragma unroll
      for (int r = 0; r < 4; ++r) mx = fmaxf(mx, sv[ct][r]);
    mx = fmaxf(mx, __shfl_xor(mx, 16));
    mx = fmaxf(mx, __shfl_xor(mx, 32));
    float nm = fmaxf(m_run, mx);
    float sc = __expf(m_run - nm);
    m_run = nm;
    float ps = 0.f;
#pragma unroll
    for (int ct = 0; ct < 4; ++ct) {
      half4 pk;
#pragma unroll
      for (int r = 0; r < 4; ++r) {
        float p = __expf(sv[ct][r] - nm);
        ps += p;
        pk[r] = (f16)p;
      }
      *(half4*)(Pw + li * 128 + (((2 * ct + (g >> 1)) ^ (li & 7)) << 4) + ((g & 1) << 3)) = pk;
    }
    ps += __shfl_xor(ps, 16);
    ps += __shfl_xor(ps, 32);
    l_run = l_run * sc + ps;
    // rescale agg rows n = g*4+r with sc from lane li=g*4+r
#pragma unroll
    for (int r = 0; r < 4; ++r) {
      float scr = __shfl(sc, (g << 4) | (g * 4 + r), 64);
#pragma unroll
      for (int ct = 0; ct < 8; ++ct) agg[ct][r] *= scr;
    }
    // PV: agg += P @ V  (P from per-wave LDS, V direct from global)
    half8 pa0 = *(const half8*)(Pw + li * 128 + (((g    ) ^ (li & 7)) << 4));
    half8 pa1 = *(const half8*)(Pw + li * 128 + (((g + 4) ^ (li & 7)) << 4));
    const char* Vc = Vg + mc * 128;
#pragma unroll
    for (int ct = 0; ct < 8; ++ct) {
      const char* vrow = Vc + (size_t)(ct * 16 + li) * 4096 + g * 16;
      half8 bv0 = *(const half8*)(vrow);
      half8 bv1 = *(const half8*)(vrow + 64);
      agg[ct] = __builtin_amdgcn_mfma_f32_16x16x32_f16(pa0, bv0, agg[ct], 0, 0, 0);
      agg[ct] = __builtin_amdgcn_mfma_f32_16x16x32_f16(pa1, bv1, agg[ct], 0, 0, 0);
    }
  }

  // epilogue: softmax denom (broadcast 1/l from lane li=n), LayerNorm
  float inv = 1.f / l_run;
  float invr[4];
#pragma unroll
  for (int r = 0; r < 4; ++r) invr[r] = __shfl(inv, (g << 4) | (g * 4 + r), 64);
  float mu[4], rs[4];
#pragma unroll
  for (int r = 0; r < 4; ++r) {
    float s = 0.f;
#pragma unroll
    for (int ct = 0; ct < 8; ++ct) { agg[ct][r] *= invr[r]; s += agg[ct][r]; }
#pragma unroll
    for (int d = 1; d < 16; d <<= 1) s += __shfl_xor(s, d);
    float m = s * (1.f / 128.f);
    float v = 0.f;
#pragma unroll
    for (int ct = 0; ct < 8; ++ct) { float d0 = agg[ct][r] - m; v += d0 * d0; }
#pragma unroll
    for (int d = 1; d < 16; d <<= 1) v += __shfl_xor(v, d);
    mu[r] = m;
    rs[r] = rsqrtf(v * (1.f / 128.f) + 1e-5f);
  }
  // LN -> f16 via per-wave LDS (transpose to A-frag layout)
#pragma unroll
  for (int r = 0; r < 4; ++r) {
    int n = g * 4 + r;
#pragma unroll
    for (int ct = 0; ct < 8; ++ct) {
      float y = (agg[ct][r] - mu[r]) * rs[r] * lw[ct] + lb[ct];
      int unit = (2 * ct + (li >> 3)) ^ (n & 7);
      *(f16*)(Pw + n * 256 + unit * 16 + (li & 7) * 2) = (f16)y;
    }
  }
  half8 af[4];
#pragma unroll
  for (int c = 0; c < 4; ++c) {
    int unit = (4 * c + g) ^ (li & 7);
    af[c] = *(const half8*)(Pw + li * 256 + unit * 16);
  }
  // fc + leaky_relu + residual q (f32) + scatter
  const f16* fw = fcwT + e * 16384;
#pragma unroll
  for (int ct = 0; ct < 8; ++ct) {
    f32x4 fa = {0.f, 0.f, 0.f, 0.f};
#pragma unroll
    for (int c = 0; c < 4; ++c) {
      half8 bf = *(const half8*)(fw + (ct * 16 + li) * 128 + c * 32 + g * 8);
      fa = __builtin_amdgcn_mfma_f32_16x16x32_f16(af[c], bf, fa, 0, 0, 0);
    }
#pragma unroll
    for (int r = 0; r < 4; ++r) {
      int nrow = n0 + w * 16 + g * 4 + r;
      float vo = fa[r];
      vo = vo > 0.f ? vo : 0.01f * vo;
      vo += q32[((size_t)e * 2048 + nrow) * 128 + ct * 16 + li];
      int gn = idx[nrow];
      out[((size_t)t * 4096 + gn) * 128 + ct * 16 + li] = vo;
    }
  }
}

extern "C" void kernel_launch(void* const* d_in, const int* in_sizes, int n_in,
                              void* d_out, int out_size, void* d_ws, size_t ws_size,
                              hipStream_t stream) {
  const float* ns      = (const float*)d_in[0];
  const float* qw      = (const float*)d_in[1];
  const float* kw      = (const float*)d_in[2];
  const float* vw      = (const float*)d_in[3];
  const float* fcw     = (const float*)d_in[4];
  const float* ln_w    = (const float*)d_in[5];
  const float* ln_b    = (const float*)d_in[6];
  const int* acc_idx   = (const int*)d_in[7];
  const int* stock_idx = (const int*)d_in[8];
  float* out = (float*)d_out;
  char* ws = (char*)d_ws;

  f16*   wT   = (f16*)ws;
  f16*   q16  = (f16*)(ws + OFF_Q16);
  float* q32  = (float*)(ws + OFF_Q32);
  f16*   K16  = (f16*)(ws + OFF_K16);
  f16*   Vt16 = (f16*)(ws + OFF_VT16);

  hipLaunchKernelGGL(prep_weights_kernel, dim3(32), dim3(256), 0, stream, qw, kw, vw, fcw, wT);
  hipLaunchKernelGGL(proj_kernel, dim3(32, 8, 2), dim3(256), 0, stream,
                     ns, acc_idx, stock_idx, wT, K16, Vt16, q16, q32);
  hipLaunchKernelGGL(attn_kernel, dim3(256), dim3(512), 0, stream,
                     K16, Vt16, q16, q32, wT + 3 * 32768, ln_w, ln_b, acc_idx, stock_idx, out);
}

// Round 4
// 107.970 us; speedup vs baseline: 2.7468x; 2.7468x over previous
//
#include <hip/hip_runtime.h>
#include <hip/hip_bf16.h>
#include <math.h>

// TemporalLayer round 4 (= round 3 with the addrspace-cast compile fix):
// LDS-staged flash attention, 2-phase double-buffered pipeline, swapped-QK
// lane-local softmax.
// ws layout (bytes):
//   [0)       qwT/kwT/vwT/fcwT  f16 [4][2][128][128]   (256 KB)
//   [262144)  q16  f16 [2][2048][128]                  (1 MB)
//   [1310720) q32  f32 [2][2048][128]                  (2 MB)
//   [3407872) K16  f16 [2][8][2048][128]               (8 MB)
//   [11796480)Vt16 f16 [2][8][128][2048]               (8 MB)  total 19.25 MB

typedef _Float16 f16;
typedef _Float16 half8 __attribute__((ext_vector_type(8)));
typedef _Float16 half4 __attribute__((ext_vector_type(4)));
typedef float f32x4 __attribute__((ext_vector_type(4)));
typedef float float4v __attribute__((ext_vector_type(4)));

#define OFF_Q16  262144
#define OFF_Q32  1310720
#define OFF_K16  3407872
#define OFF_VT16 11796480

__device__ __forceinline__ void async16(const void* g, void* l) {
  __builtin_amdgcn_global_load_lds((const __attribute__((address_space(1))) void*)g,
                                   (__attribute__((address_space(3))) void*)l, 16, 0, 0);
}

__global__ void prep_weights_kernel(const float* __restrict__ qw, const float* __restrict__ kw,
                                    const float* __restrict__ vw, const float* __restrict__ fcw,
                                    f16* __restrict__ wT) {
  int b = blockIdx.x;                 // 32 blocks: wsel*8 + e*4 + part
  int wsel = b >> 3, e = (b >> 2) & 1, part = b & 3;
  const float* src = (wsel == 0) ? qw : (wsel == 1) ? kw : (wsel == 2) ? vw : fcw;
  src += e * 16384;
  f16* dst = wT + (size_t)wsel * 32768 + e * 16384;
  for (int i = part * 4096 + threadIdx.x; i < (part + 1) * 4096; i += 256) {
    int v = i >> 7, u = i & 127;
    dst[i] = (f16)src[u * 128 + v];   // wT[v][u] = w[u][v]
  }
}

// grid (32, 8, 2): 64 nodes per block, 4 waves x 16 rows
__global__ __launch_bounds__(256) void proj_kernel(
    const float* __restrict__ ns, const int* __restrict__ acc_idx, const int* __restrict__ stock_idx,
    const f16* __restrict__ wT, f16* __restrict__ K16, f16* __restrict__ Vt16,
    f16* __restrict__ q16, float* __restrict__ q32) {
  const int e = blockIdx.z, t = blockIdx.y, nt = blockIdx.x;
  const int tid = threadIdx.x, w = tid >> 6, l = tid & 63;
  const int g = l >> 4, li = l & 15;
  const int* idx = e ? stock_idx : acc_idx;
  const int mA = nt * 64 + w * 16 + li;
  const int gnode = idx[mA];
  const float* srow = ns + ((size_t)t * 4096 + gnode) * 128;
  half8 a[4];
#pragma unroll
  for (int c = 0; c < 4; ++c) {
    const float4v* p = (const float4v*)(srow + c * 32 + g * 8);
    float4v x0 = p[0], x1 = p[1];
    half8 h;
    h[0]=(f16)x0[0]; h[1]=(f16)x0[1]; h[2]=(f16)x0[2]; h[3]=(f16)x0[3];
    h[4]=(f16)x1[0]; h[5]=(f16)x1[1]; h[6]=(f16)x1[2]; h[7]=(f16)x1[3];
    a[c] = h;
  }
  const f16* qwT = wT + 0     + e * 16384;
  const f16* kwT = wT + 32768 + e * 16384;
  const f16* vwT = wT + 65536 + e * 16384;

  // K = s @ kw -> K16[e][t][m][v]
#pragma unroll
  for (int ct = 0; ct < 8; ++ct) {
    f32x4 acc = {0.f, 0.f, 0.f, 0.f};
#pragma unroll
    for (int c = 0; c < 4; ++c) {
      half8 b = *(const half8*)(kwT + (ct * 16 + li) * 128 + c * 32 + g * 8);
      acc = __builtin_amdgcn_mfma_f32_16x16x32_f16(a[c], b, acc, 0, 0, 0);
    }
#pragma unroll
    for (int r = 0; r < 4; ++r) {
      int mrow = nt * 64 + w * 16 + g * 4 + r;
      K16[(((size_t)e * 8 + t) * 2048 + mrow) * 128 + ct * 16 + li] = (f16)acc[r];
    }
  }
  // V = s @ vw -> stored transposed Vt16[e][t][v][m], packed half4 writes
#pragma unroll
  for (int ct = 0; ct < 8; ++ct) {
    f32x4 acc = {0.f, 0.f, 0.f, 0.f};
#pragma unroll
    for (int c = 0; c < 4; ++c) {
      half8 b = *(const half8*)(vwT + (ct * 16 + li) * 128 + c * 32 + g * 8);
      acc = __builtin_amdgcn_mfma_f32_16x16x32_f16(a[c], b, acc, 0, 0, 0);
    }
    half4 pk;
#pragma unroll
    for (int r = 0; r < 4; ++r) pk[r] = (f16)acc[r];
    int m0 = nt * 64 + w * 16 + g * 4;
    *(half4*)(Vt16 + (((size_t)e * 8 + t) * 128 + ct * 16 + li) * 2048 + m0) = pk;
  }
  // q = s[-1] @ qw (f16 + f32)
  if (t == 7) {
#pragma unroll
    for (int ct = 0; ct < 8; ++ct) {
      f32x4 acc = {0.f, 0.f, 0.f, 0.f};
#pragma unroll
      for (int c = 0; c < 4; ++c) {
        half8 b = *(const half8*)(qwT + (ct * 16 + li) * 128 + c * 32 + g * 8);
        acc = __builtin_amdgcn_mfma_f32_16x16x32_f16(a[c], b, acc, 0, 0, 0);
      }
#pragma unroll
      for (int r = 0; r < 4; ++r) {
        int mrow = nt * 64 + w * 16 + g * 4 + r;
        size_t o = ((size_t)e * 2048 + mrow) * 128 + ct * 16 + li;
        q16[o] = (f16)acc[r];
        q32[o] = acc[r];
      }
    }
  }
}

// 512 blocks x 256 threads (4 waves x 16 q-rows). Double-buffered LDS staging.
// bid decode: XCD x = bid&7 owns (e,t) = x + 8*(bid>>8); nt = (bid>>3)&31.
__global__ __launch_bounds__(256, 2) void attn_kernel(
    const f16* __restrict__ K16, const f16* __restrict__ Vt16,
    const f16* __restrict__ q16, const float* __restrict__ q32,
    const f16* __restrict__ fcwT, const float* __restrict__ ln_w, const float* __restrict__ ln_b,
    const int* __restrict__ acc_idx, const int* __restrict__ stock_idx,
    float* __restrict__ out) {
  __shared__ __align__(16) char smem[73728];   // 2x16K K | 2x16K V | 4x2K P
  const int bid = blockIdx.x;
  const int et = (bid & 7) + 8 * (bid >> 8);
  const int nt = (bid >> 3) & 31;
  const int e = et >> 3, t = et & 7;
  const int n0 = nt * 64;
  const int tid = threadIdx.x, w = tid >> 6, l = tid & 63;
  const int g = l >> 4, li = l & 15;
  const int* idx = e ? stock_idx : acc_idx;

  char* Pw = smem + 65536 + w * 2048;          // per-wave P [16 n][64 m] f16

  half8 qa[4];
  {
    const f16* qrow = q16 + ((size_t)e * 2048 + n0 + w * 16 + li) * 128;
#pragma unroll
    for (int c = 0; c < 4; ++c) qa[c] = *(const half8*)(qrow + c * 32 + g * 8);
  }
  float lw[8], lb[8];
#pragma unroll
  for (int ct = 0; ct < 8; ++ct) { lw[ct] = ln_w[ct * 16 + li]; lb[ct] = ln_b[ct * 16 + li]; }

  f32x4 agg[8];
#pragma unroll
  for (int ct = 0; ct < 8; ++ct) agg[ct] = (f32x4){0.f, 0.f, 0.f, 0.f};
  float m_run = -INFINITY, l_run = 0.f;        // stats for q-row n = li

  const char* Kg = (const char*)(K16 + ((size_t)e * 8 + t) * 2048 * 128);
  const char* Vg = (const char*)(Vt16 + ((size_t)e * 8 + t) * 128 * 2048);

  // staging thread->slot decode (uniform per thread)
  const int slotb = w * 256;                   // + i*64 + l
  // K: row = slot>>4, unit = slot&15 ; V: row = slot>>3, unit = slot&7

#define STAGE(bufoff, mc_)                                                        \
  {                                                                               \
    char* Ks_ = smem + (bufoff);                                                  \
    char* Vs_ = smem + 32768 + (bufoff);                                          \
    _Pragma("unroll")                                                             \
    for (int i = 0; i < 4; ++i) {                                                 \
      int slot = slotb + i * 64 + l;                                              \
      int row = slot >> 4, unit = slot & 15;                                      \
      const char* src = Kg + ((size_t)((mc_) * 64 + row)) * 256 + ((unit ^ (row & 7)) * 16); \
      async16(src, Ks_ + (slotb + i * 64) * 16);                                  \
    }                                                                             \
    _Pragma("unroll")                                                             \
    for (int i = 0; i < 4; ++i) {                                                 \
      int slot = slotb + i * 64 + l;                                              \
      int row = slot >> 3, unit = slot & 7;                                       \
      const char* src = Vg + (size_t)row * 4096 + (mc_) * 128 + ((unit ^ (row & 7)) * 16);   \
      async16(src, Vs_ + (slotb + i * 64) * 16);                                  \
    }                                                                             \
  }

  // prologue: stage chunk 0
  STAGE(0, 0);
  asm volatile("s_waitcnt vmcnt(0)" ::: "memory");
  __syncthreads();

  int cur = 0;
  for (int mc = 0; mc < 32; ++mc) {
    // issue next-chunk stage first; it lands during compute below
    if (mc != 31) STAGE(cur ^ 16384, mc + 1);
    __builtin_amdgcn_sched_barrier(0);
    char* Ks = smem + cur;
    char* Vs = smem + 32768 + cur;

    // S^T = K @ Q^T : sv[ct][r] = S[m = mc*64+ct*16+g*4+r][n = li]
    float sv[4][4];
#pragma unroll
    for (int ct = 0; ct < 4; ++ct) {
      f32x4 sa = {0.f, 0.f, 0.f, 0.f};
#pragma unroll
      for (int c = 0; c < 4; ++c) {
        int row = ct * 16 + li;
        half8 bk = *(const half8*)(Ks + row * 256 + (((c * 4 + g) ^ (row & 7)) * 16));
        sa = __builtin_amdgcn_mfma_f32_16x16x32_f16(bk, qa[c], sa, 0, 0, 0);
      }
#pragma unroll
      for (int r = 0; r < 4; ++r) sv[ct][r] = sa[r];
    }
    // online softmax: row n=li fully in-lane; cross-g reduce with 2 shfls
    float mx = sv[0][0];
#pragma unroll
    for (int ct = 0; ct < 4; ++ct)
#pragma unroll
      for (int r = 0; r < 4; ++r) mx = fmaxf(mx, sv[ct][r]);
    mx = fmaxf(mx, __shfl_xor(mx, 16));
    mx = fmaxf(mx, __shfl_xor(mx, 32));
    float nm = fmaxf(m_run, mx);
    float sc = __expf(m_run - nm);
    m_run = nm;
    float ps = 0.f;
#pragma unroll
    for (int ct = 0; ct < 4; ++ct) {
      half4 pk;
#pragma unroll
      for (int r = 0; r < 4; ++r) {
        float p = __expf(sv[ct][r] - nm);
        ps += p;
        pk[r] = (f16)p;
      }
      *(half4*)(Pw + li * 128 + (((2 * ct + (g >> 1)) ^ (li & 7)) << 4) + ((g & 1) << 3)) = pk;
    }
    ps += __shfl_xor(ps, 16);
    ps += __shfl_xor(ps, 32);
    l_run = l_run * sc + ps;
    // rescale agg rows n = g*4+r with sc from a lane whose li == n
#pragma unroll
    for (int r = 0; r < 4; ++r) {
      float scr = __shfl(sc, (g << 4) | (g * 4 + r), 64);
#pragma unroll
      for (int ct = 0; ct < 8; ++ct) agg[ct][r] *= scr;
    }
    asm volatile("s_waitcnt lgkmcnt(0)" ::: "memory");
    __builtin_amdgcn_sched_barrier(0);
    // PV: agg += P @ V (both from LDS)
    half8 pa0 = *(const half8*)(Pw + li * 128 + (((g    ) ^ (li & 7)) << 4));
    half8 pa1 = *(const half8*)(Pw + li * 128 + (((g + 4) ^ (li & 7)) << 4));
#pragma unroll
    for (int ct = 0; ct < 8; ++ct) {
      int row = ct * 16 + li;
      half8 bv0 = *(const half8*)(Vs + row * 128 + (((g    ) ^ (row & 7)) << 4));
      half8 bv1 = *(const half8*)(Vs + row * 128 + (((g + 4) ^ (row & 7)) << 4));
      agg[ct] = __builtin_amdgcn_mfma_f32_16x16x32_f16(pa0, bv0, agg[ct], 0, 0, 0);
      agg[ct] = __builtin_amdgcn_mfma_f32_16x16x32_f16(pa1, bv1, agg[ct], 0, 0, 0);
    }
    // next-chunk stage must have landed; all waves done reading cur
    __syncthreads();
    cur ^= 16384;
  }
#undef STAGE

  // epilogue: softmax denom (broadcast 1/l from lane with li=n), LayerNorm
  float inv = 1.f / l_run;
  float invr[4];
#pragma unroll
  for (int r = 0; r < 4; ++r) invr[r] = __shfl(inv, (g << 4) | (g * 4 + r), 64);
  float mu[4], rs[4];
#pragma unroll
  for (int r = 0; r < 4; ++r) {
    float s = 0.f;
#pragma unroll
    for (int ct = 0; ct < 8; ++ct) { agg[ct][r] *= invr[r]; s += agg[ct][r]; }
#pragma unroll
    for (int d = 1; d < 16; d <<= 1) s += __shfl_xor(s, d);
    float m = s * (1.f / 128.f);
    float v = 0.f;
#pragma unroll
    for (int ct = 0; ct < 8; ++ct) { float d0 = agg[ct][r] - m; v += d0 * d0; }
#pragma unroll
    for (int d = 1; d < 16; d <<= 1) v += __shfl_xor(v, d);
    mu[r] = m;
    rs[r] = rsqrtf(v * (1.f / 128.f) + 1e-5f);
  }
  // LN -> f16 via per-wave LDS region (Kbuf now free; 4KB per wave)
  char* As = smem + w * 4096;
#pragma unroll
  for (int r = 0; r < 4; ++r) {
    int n = g * 4 + r;
#pragma unroll
    for (int ct = 0; ct < 8; ++ct) {
      float y = (agg[ct][r] - mu[r]) * rs[r] * lw[ct] + lb[ct];
      int unit = (2 * ct + (li >> 3)) ^ (n & 7);
      *(f16*)(As + n * 256 + unit * 16 + (li & 7) * 2) = (f16)y;
    }
  }
  asm volatile("s_waitcnt lgkmcnt(0)" ::: "memory");
  __builtin_amdgcn_sched_barrier(0);
  half8 af[4];
#pragma unroll
  for (int c = 0; c < 4; ++c) {
    int unit = (4 * c + g) ^ (li & 7);
    af[c] = *(const half8*)(As + li * 256 + unit * 16);
  }
  // fc + leaky_relu + residual q (f32) + scatter
  const f16* fw = fcwT + e * 16384;
#pragma unroll
  for (int ct = 0; ct < 8; ++ct) {
    f32x4 fa = {0.f, 0.f, 0.f, 0.f};
#pragma unroll
    for (int c = 0; c < 4; ++c) {
      half8 bf = *(const half8*)(fw + (ct * 16 + li) * 128 + c * 32 + g * 8);
      fa = __builtin_amdgcn_mfma_f32_16x16x32_f16(af[c], bf, fa, 0, 0, 0);
    }
#pragma unroll
    for (int r = 0; r < 4; ++r) {
      int nrow = n0 + w * 16 + g * 4 + r;
      float vo = fa[r];
      vo = vo > 0.f ? vo : 0.01f * vo;
      vo += q32[((size_t)e * 2048 + nrow) * 128 + ct * 16 + li];
      int gn = idx[nrow];
      out[((size_t)t * 4096 + gn) * 128 + ct * 16 + li] = vo;
    }
  }
}

extern "C" void kernel_launch(void* const* d_in, const int* in_sizes, int n_in,
                              void* d_out, int out_size, void* d_ws, size_t ws_size,
                              hipStream_t stream) {
  const float* ns      = (const float*)d_in[0];
  const float* qw      = (const float*)d_in[1];
  const float* kw      = (const float*)d_in[2];
  const float* vw      = (const float*)d_in[3];
  const float* fcw     = (const float*)d_in[4];
  const float* ln_w    = (const float*)d_in[5];
  const float* ln_b    = (const float*)d_in[6];
  const int* acc_idx   = (const int*)d_in[7];
  const int* stock_idx = (const int*)d_in[8];
  float* out = (float*)d_out;
  char* ws = (char*)d_ws;

  f16*   wT   = (f16*)ws;
  f16*   q16  = (f16*)(ws + OFF_Q16);
  float* q32  = (float*)(ws + OFF_Q32);
  f16*   K16  = (f16*)(ws + OFF_K16);
  f16*   Vt16 = (f16*)(ws + OFF_VT16);

  hipLaunchKernelGGL(prep_weights_kernel, dim3(32), dim3(256), 0, stream, qw, kw, vw, fcw, wT);
  hipLaunchKernelGGL(proj_kernel, dim3(32, 8, 2), dim3(256), 0, stream,
                     ns, acc_idx, stock_idx, wT, K16, Vt16, q16, q32);
  hipLaunchKernelGGL(attn_kernel, dim3(512), dim3(256), 0, stream,
                     K16, Vt16, q16, q32, wT + 3 * 32768, ln_w, ln_b, acc_idx, stock_idx, out);
}